// Round 1
// baseline (1162.473 us; speedup 1.0000x reference)
//
#include <hip/hip_runtime.h>

#define L 4096
#define D 512
#define NCH 16   // context n-chunks

// ---------------------------------------------------------------------------
// Kernel 1: qkv[b, o, l] = sum_d Wqkv[o,d] * x[b,l,d]
// grid (L/64, 1536/64, B), block 256. 64x64 tile, 4x4 per thread, BK=16.
// ---------------------------------------------------------------------------
__global__ __launch_bounds__(256) void qkv_gemm(const float* __restrict__ x,
                                                const float* __restrict__ W,
                                                float* __restrict__ qkv) {
    __shared__ float sA[16][68];  // sA[kk][oo]  (pad 68 -> 16B-aligned rows)
    __shared__ float sB[16][68];  // sB[kk][ll]
    const int b  = blockIdx.z;
    const int o0 = blockIdx.y * 64;
    const int l0 = blockIdx.x * 64;
    const int t  = threadIdx.x;
    const int tx = t % 16, ty = t / 16;
    const float* xb = x + (size_t)b * L * D;
    float acc[4][4] = {};
    for (int k0 = 0; k0 < D; k0 += 16) {
        {   // A tile: W[o0+i][k0+j], j=t%16, i=t/16 (+16r)
            int j = t % 16, i = t / 16;
#pragma unroll
            for (int r = 0; r < 4; r++)
                sA[j][i + 16 * r] = W[(size_t)(o0 + i + 16 * r) * D + k0 + j];
        }
        {   // B tile: x[b][l0+ll][k0+kk], kk=t%16, ll=t/16 (+16r)
            int kk = t % 16, ll = t / 16;
#pragma unroll
            for (int r = 0; r < 4; r++)
                sB[kk][ll + 16 * r] = xb[(size_t)(l0 + ll + 16 * r) * D + k0 + kk];
        }
        __syncthreads();
#pragma unroll
        for (int kk = 0; kk < 16; kk++) {
            float a[4], bb[4];
#pragma unroll
            for (int i = 0; i < 4; i++) a[i] = sA[kk][ty * 4 + i];
#pragma unroll
            for (int j = 0; j < 4; j++) bb[j] = sB[kk][tx * 4 + j];
#pragma unroll
            for (int i = 0; i < 4; i++)
#pragma unroll
                for (int j = 0; j < 4; j++) acc[i][j] += a[i] * bb[j];
        }
        __syncthreads();
    }
    float* out = qkv + (size_t)b * 1536 * L;
#pragma unroll
    for (int i = 0; i < 4; i++) {
        int o = o0 + ty * 4 + i;
        float4 v = make_float4(acc[i][0], acc[i][1], acc[i][2], acc[i][3]);
        *(float4*)(out + (size_t)o * L + l0 + tx * 4) = v;
    }
}

// ---------------------------------------------------------------------------
// Kernel 2: softmax over L for k rows. grid = B*H*C = 4096 blocks, block 256.
// ---------------------------------------------------------------------------
__global__ __launch_bounds__(256) void softmax_k(float* __restrict__ qkv) {
    const int r = blockIdx.x;
    const int b = r >> 9, hc = r & 511;
    float* row = qkv + (size_t)b * 1536 * L + (size_t)(512 + hc) * L;
    __shared__ float sred[4];
    const int t = threadIdx.x;
    float v[16];
    float m = -1e30f;
#pragma unroll
    for (int i = 0; i < 16; i++) {
        v[i] = row[t + 256 * i];
        m = fmaxf(m, v[i]);
    }
#pragma unroll
    for (int off = 32; off > 0; off >>= 1) m = fmaxf(m, __shfl_down(m, off, 64));
    if ((t & 63) == 0) sred[t >> 6] = m;
    __syncthreads();
    const float m4 = fmaxf(fmaxf(sred[0], sred[1]), fmaxf(sred[2], sred[3]));
    float s = 0.f;
#pragma unroll
    for (int i = 0; i < 16; i++) {
        v[i] = __expf(v[i] - m4);
        s += v[i];
    }
#pragma unroll
    for (int off = 32; off > 0; off >>= 1) s += __shfl_down(s, off, 64);
    __syncthreads();  // protect sred reuse
    if ((t & 63) == 0) sred[t >> 6] = s;
    __syncthreads();
    const float inv = 1.0f / (sred[0] + sred[1] + sred[2] + sred[3]);
#pragma unroll
    for (int i = 0; i < 16; i++) row[t + 256 * i] = v[i] * inv;
}

// ---------------------------------------------------------------------------
// Kernel 3: softmax over C (=64) for q columns. grid = B*H*(L/256) = 1024.
// ---------------------------------------------------------------------------
__global__ __launch_bounds__(256) void softmax_q(float* __restrict__ qkv) {
    const int blk = blockIdx.x;
    const int lc = blk & 15, bh = blk >> 4;
    const int b = bh >> 3, h = bh & 7;
    const int l = lc * 256 + threadIdx.x;
    float* base = qkv + (size_t)b * 1536 * L + (size_t)(h * 64) * L + l;
    float v[64];
    float m = -1e30f;
#pragma unroll
    for (int c = 0; c < 64; c++) {
        v[c] = base[(size_t)c * L];
        m = fmaxf(m, v[c]);
    }
    float s = 0.f;
#pragma unroll
    for (int c = 0; c < 64; c++) {
        v[c] = __expf(v[c] - m);
        s += v[c];
    }
    const float inv = 1.0f / s;
#pragma unroll
    for (int c = 0; c < 64; c++) base[(size_t)c * L] = v[c] * inv;
}

// ---------------------------------------------------------------------------
// Kernel 4: context partials. ctx_part[chunk][bh][d][e] = sum over n-range of
// k[d,n]*v[e,n]. grid (NCH, B*H), block 256, 4x4 per thread.
// ---------------------------------------------------------------------------
__global__ __launch_bounds__(256) void context_partial(const float* __restrict__ qkv,
                                                       float* __restrict__ ctx) {
    const int chunk = blockIdx.x;
    const int bh = blockIdx.y;
    const int b = bh >> 3, h = bh & 7;
    const float* kbase = qkv + (size_t)b * 1536 * L + (size_t)(512 + h * 64) * L;
    const float* vbase = qkv + (size_t)b * 1536 * L + (size_t)(1024 + h * 64) * L;
    __shared__ float sk[64][65];  // [d][nn]
    __shared__ float sv[64][65];  // [e][nn]
    const int t = threadIdx.x;
    const int tx = t % 16, ty = t / 16;
    float acc[4][4] = {};
    const int n_start = chunk * (L / NCH);
    for (int ns = 0; ns < L / NCH; ns += 64) {
        const int n0 = n_start + ns;
        const int nn = t % 64, d0 = t / 64;
#pragma unroll
        for (int r = 0; r < 16; r++) {
            int d = d0 + r * 4;
            sk[d][nn] = kbase[(size_t)d * L + n0 + nn];
            sv[d][nn] = vbase[(size_t)d * L + n0 + nn];
        }
        __syncthreads();
#pragma unroll 8
        for (int q = 0; q < 64; q++) {
            float a[4], bb[4];
#pragma unroll
            for (int i = 0; i < 4; i++) a[i] = sk[ty * 4 + i][q];
#pragma unroll
            for (int j = 0; j < 4; j++) bb[j] = sv[tx * 4 + j][q];
#pragma unroll
            for (int i = 0; i < 4; i++)
#pragma unroll
                for (int j = 0; j < 4; j++) acc[i][j] += a[i] * bb[j];
        }
        __syncthreads();
    }
    float* cp = ctx + ((size_t)chunk * 64 + bh) * 4096;
#pragma unroll
    for (int i = 0; i < 4; i++) {
        float4 v = make_float4(acc[i][0], acc[i][1], acc[i][2], acc[i][3]);
        *(float4*)(cp + (ty * 4 + i) * 64 + tx * 4) = v;
    }
}

// ---------------------------------------------------------------------------
// Kernel 5: out[b, h*64+e, n] = sum_d context[d,e] * q[d,n].
// Writes into the (dead) k-region of qkv. grid (L/256, B*H), block 256.
// ---------------------------------------------------------------------------
__global__ __launch_bounds__(256) void pv_kernel(float* __restrict__ qkv,
                                                 const float* __restrict__ ctx) {
    const int lc = blockIdx.x;
    const int bh = blockIdx.y;
    const int b = bh >> 3, h = bh & 7;
    __shared__ float sc[4096];  // context[d][e], d-major
    const int t = threadIdx.x;
#pragma unroll
    for (int r = 0; r < 16; r++) {
        const int idx = t + r * 256;
        float s = 0.f;
        for (int ch = 0; ch < NCH; ch++)
            s += ctx[((size_t)ch * 64 + bh) * 4096 + idx];
        sc[idx] = s;
    }
    __syncthreads();
    const float* qbase = qkv + (size_t)b * 1536 * L + (size_t)(h * 64) * L;
    const int n = lc * 256 + t;
    float acc[64] = {};
#pragma unroll 4
    for (int d = 0; d < 64; d++) {
        const float qv = qbase[(size_t)d * L + n];
#pragma unroll
        for (int e = 0; e < 64; e++) acc[e] += sc[d * 64 + e] * qv;
    }
    float* ob = qkv + (size_t)b * 1536 * L + (size_t)(512 + h * 64) * L;
#pragma unroll
    for (int e = 0; e < 64; e++) ob[(size_t)e * L + n] = acc[e];
}

// ---------------------------------------------------------------------------
// Kernel 6: y[b,l,d] = sum_c out[b,c,l] * Wout[d,c] + bout[d]
// grid (L/64, 512/64, B), block 256. Same tiling as kernel 1.
// ---------------------------------------------------------------------------
__global__ __launch_bounds__(256) void out_gemm(const float* __restrict__ qkv,
                                                const float* __restrict__ Wout,
                                                const float* __restrict__ bout,
                                                float* __restrict__ y) {
    __shared__ float sA[16][68];  // [kk][ll]
    __shared__ float sB[16][68];  // [kk][dd]
    const int b  = blockIdx.z;
    const int d0 = blockIdx.y * 64;
    const int l0 = blockIdx.x * 64;
    const int t  = threadIdx.x;
    const int tx = t % 16, ty = t / 16;
    const float* ob = qkv + (size_t)b * 1536 * L + (size_t)512 * L;
    float acc[4][4] = {};
    for (int c0 = 0; c0 < 512; c0 += 16) {
        {   // A tile: out[c0+kk][l0+ll]
            int kk4 = t / 64, ll = t % 64;
#pragma unroll
            for (int r = 0; r < 4; r++) {
                int kk = kk4 + r * 4;
                sA[kk][ll] = ob[(size_t)(c0 + kk) * L + l0 + ll];
            }
        }
        {   // B tile: Wout[d0+dd][c0+kk]
            int kk = t % 16, dd = t / 16;
#pragma unroll
            for (int r = 0; r < 4; r++)
                sB[kk][dd + 16 * r] = Wout[(size_t)(d0 + dd + 16 * r) * 512 + c0 + kk];
        }
        __syncthreads();
#pragma unroll
        for (int kk = 0; kk < 16; kk++) {
            float a[4], bb[4];
#pragma unroll
            for (int i = 0; i < 4; i++) a[i] = sA[kk][ty * 4 + i];
#pragma unroll
            for (int j = 0; j < 4; j++) bb[j] = sB[kk][tx * 4 + j];
#pragma unroll
            for (int i = 0; i < 4; i++)
#pragma unroll
                for (int j = 0; j < 4; j++) acc[i][j] += a[i] * bb[j];
        }
        __syncthreads();
    }
#pragma unroll
    for (int i = 0; i < 4; i++) {
        const int l = l0 + ty * 4 + i;
        float4 v;
        v.x = acc[i][0] + bout[d0 + tx * 4 + 0];
        v.y = acc[i][1] + bout[d0 + tx * 4 + 1];
        v.z = acc[i][2] + bout[d0 + tx * 4 + 2];
        v.w = acc[i][3] + bout[d0 + tx * 4 + 3];
        *(float4*)(y + (size_t)b * L * 512 + (size_t)l * 512 + d0 + tx * 4) = v;
    }
}

// ---------------------------------------------------------------------------
extern "C" void kernel_launch(void* const* d_in, const int* in_sizes, int n_in,
                              void* d_out, int out_size, void* d_ws, size_t ws_size,
                              hipStream_t stream) {
    const float* x    = (const float*)d_in[0];
    const float* Wqkv = (const float*)d_in[1];
    const float* Wout = (const float*)d_in[2];
    const float* bout = (const float*)d_in[3];
    float* y = (float*)d_out;

    float* qkv = (float*)d_ws;                          // 8*1536*4096 floats (201 MB)
    float* ctx = qkv + (size_t)8 * 1536 * L;            // NCH*64*4096 floats (17 MB)

    qkv_gemm<<<dim3(L / 64, 1536 / 64, 8), 256, 0, stream>>>(x, Wqkv, qkv);
    softmax_k<<<dim3(4096), 256, 0, stream>>>(qkv);
    softmax_q<<<dim3(1024), 256, 0, stream>>>(qkv);
    context_partial<<<dim3(NCH, 64), 256, 0, stream>>>(qkv, ctx);
    pv_kernel<<<dim3(L / 256, 64), 256, 0, stream>>>(qkv, ctx);
    out_gemm<<<dim3(L / 64, 512 / 64, 8), 256, 0, stream>>>(qkv, Wout, bout, y);
}

// Round 2
// 391.027 us; speedup vs baseline: 2.9729x; 2.9729x over previous
//
#include <hip/hip_runtime.h>

#define L 4096
#define D 512
#define NCH 16   // context n-chunks

typedef __bf16 bf16x8 __attribute__((ext_vector_type(8)));
typedef float  f32x4  __attribute__((ext_vector_type(4)));

__device__ __forceinline__ void load_lds16(const void* g, void* l) {
    __builtin_amdgcn_global_load_lds(
        (const __attribute__((address_space(1))) void*)g,
        (__attribute__((address_space(3))) void*)l, 16, 0, 0);
}

// ---------------------------------------------------------------------------
// f32 -> bf16 conversion (8 elems / thread, 16B stores)
// ---------------------------------------------------------------------------
__global__ __launch_bounds__(256) void f32_to_bf16(const float* __restrict__ in,
                                                   __bf16* __restrict__ out, int n8) {
    int i = blockIdx.x * 256 + threadIdx.x;
    if (i >= n8) return;
    const float4* p = (const float4*)in + (size_t)i * 2;
    float4 a = p[0], b = p[1];
    bf16x8 o = {(__bf16)a.x, (__bf16)a.y, (__bf16)a.z, (__bf16)a.w,
                (__bf16)b.x, (__bf16)b.y, (__bf16)b.z, (__bf16)b.w};
    *(bf16x8*)(out + (size_t)i * 8) = o;
}

// ---------------------------------------------------------------------------
// Generic TN bf16 MFMA GEMM: C[b][m][n] = sum_k A[b][m][k] * B[b][n][k] (+bias[n])
// Block tile 128x128, BK=32, 4 waves (2x2), each wave 64x64 via 4x4 MFMA tiles.
// ---------------------------------------------------------------------------
template <int M, int N, int K>
__global__ __launch_bounds__(256) void gemm_bf16_mfma(
    const __bf16* __restrict__ A, size_t aStride,
    const __bf16* __restrict__ B, size_t bStride,
    float* __restrict__ C, size_t cStride,
    const float* __restrict__ bias) {
    __shared__ __align__(16) __bf16 sA[128 * 32];
    __shared__ __align__(16) __bf16 sB[128 * 32];
    const int b  = blockIdx.z;
    const int m0 = blockIdx.y * 128;
    const int n0 = blockIdx.x * 128;
    const int t    = threadIdx.x;
    const int wave = t >> 6, lane = t & 63;
    const int wm = (wave & 1) * 64, wn = (wave >> 1) * 64;
    const __bf16* Ab = A + (size_t)b * aStride;
    const __bf16* Bb = B + (size_t)b * bStride;
    float* Cb = C + (size_t)b * cStride;

    f32x4 acc[4][4];
#pragma unroll
    for (int i = 0; i < 4; i++)
#pragma unroll
        for (int j = 0; j < 4; j++) acc[i][j] = (f32x4)(0.0f);

    const int fr = lane & 15;          // m (A) / n (B) within 16-tile
    const int kq = (lane >> 4) * 8;    // k offset within 32

    for (int k0 = 0; k0 < K; k0 += 32) {
        __syncthreads();
#pragma unroll
        for (int c = 0; c < 2; c++) {
            const int idx = c * 256 + t;
            const int row = idx >> 2, kc = idx & 3;
            load_lds16(Ab + (size_t)(m0 + row) * K + k0 + kc * 8, &sA[idx * 8]);
            load_lds16(Bb + (size_t)(n0 + row) * K + k0 + kc * 8, &sB[idx * 8]);
        }
        __syncthreads();
        bf16x8 af[4], bfr[4];
#pragma unroll
        for (int i = 0; i < 4; i++) {
            af[i]  = *(const bf16x8*)&sA[(wm + i * 16 + fr) * 32 + kq];
            bfr[i] = *(const bf16x8*)&sB[(wn + i * 16 + fr) * 32 + kq];
        }
#pragma unroll
        for (int i = 0; i < 4; i++)
#pragma unroll
            for (int j = 0; j < 4; j++)
                acc[i][j] = __builtin_amdgcn_mfma_f32_16x16x32_bf16(af[i], bfr[j], acc[i][j], 0, 0, 0);
    }

    const int col = lane & 15, rbase = (lane >> 4) * 4;
#pragma unroll
    for (int j = 0; j < 4; j++) {
        const int n = n0 + wn + j * 16 + col;
        const float bv = bias ? bias[n] : 0.0f;
#pragma unroll
        for (int i = 0; i < 4; i++) {
#pragma unroll
            for (int r = 0; r < 4; r++) {
                const int m = m0 + wm + i * 16 + rbase + r;
                Cb[(size_t)m * N + n] = acc[i][j][r] + bv;
            }
        }
    }
}

// ---------------------------------------------------------------------------
// softmax over L for k rows. grid = B*H*C = 4096 blocks, block 256.
// ---------------------------------------------------------------------------
__global__ __launch_bounds__(256) void softmax_k(float* __restrict__ qkv) {
    const int r = blockIdx.x;
    const int b = r >> 9, hc = r & 511;
    float* row = qkv + (size_t)b * 1536 * L + (size_t)(512 + hc) * L;
    __shared__ float sred[4];
    const int t = threadIdx.x;
    float v[16];
    float m = -1e30f;
#pragma unroll
    for (int i = 0; i < 16; i++) {
        v[i] = row[t + 256 * i];
        m = fmaxf(m, v[i]);
    }
#pragma unroll
    for (int off = 32; off > 0; off >>= 1) m = fmaxf(m, __shfl_down(m, off, 64));
    if ((t & 63) == 0) sred[t >> 6] = m;
    __syncthreads();
    const float m4 = fmaxf(fmaxf(sred[0], sred[1]), fmaxf(sred[2], sred[3]));
    float s = 0.f;
#pragma unroll
    for (int i = 0; i < 16; i++) {
        v[i] = __expf(v[i] - m4);
        s += v[i];
    }
#pragma unroll
    for (int off = 32; off > 0; off >>= 1) s += __shfl_down(s, off, 64);
    __syncthreads();
    if ((t & 63) == 0) sred[t >> 6] = s;
    __syncthreads();
    const float inv = 1.0f / (sred[0] + sred[1] + sred[2] + sred[3]);
#pragma unroll
    for (int i = 0; i < 16; i++) row[t + 256 * i] = v[i] * inv;
}

// ---------------------------------------------------------------------------
// softmax over C (=64) for q columns. grid = B*H*(L/256) = 1024.
// ---------------------------------------------------------------------------
__global__ __launch_bounds__(256) void softmax_q(float* __restrict__ qkv) {
    const int blk = blockIdx.x;
    const int lc = blk & 15, bh = blk >> 4;
    const int b = bh >> 3, h = bh & 7;
    const int l = lc * 256 + threadIdx.x;
    float* base = qkv + (size_t)b * 1536 * L + (size_t)(h * 64) * L + l;
    float v[64];
    float m = -1e30f;
#pragma unroll
    for (int c = 0; c < 64; c++) {
        v[c] = base[(size_t)c * L];
        m = fmaxf(m, v[c]);
    }
    float s = 0.f;
#pragma unroll
    for (int c = 0; c < 64; c++) {
        v[c] = __expf(v[c] - m);
        s += v[c];
    }
    const float inv = 1.0f / s;
#pragma unroll
    for (int c = 0; c < 64; c++) base[(size_t)c * L] = v[c] * inv;
}

// ---------------------------------------------------------------------------
// context partials. ctx[chunk][bh][d][e] = sum_{n in chunk} k[d,n]*v[e,n].
// ---------------------------------------------------------------------------
__global__ __launch_bounds__(256) void context_partial(const float* __restrict__ qkv,
                                                       float* __restrict__ ctx) {
    const int chunk = blockIdx.x;
    const int bh = blockIdx.y;
    const int b = bh >> 3, h = bh & 7;
    const float* kbase = qkv + (size_t)b * 1536 * L + (size_t)(512 + h * 64) * L;
    const float* vbase = qkv + (size_t)b * 1536 * L + (size_t)(1024 + h * 64) * L;
    __shared__ float sk[64][65];
    __shared__ float sv[64][65];
    const int t = threadIdx.x;
    const int tx = t % 16, ty = t / 16;
    float acc[4][4] = {};
    const int n_start = chunk * (L / NCH);
    for (int ns = 0; ns < L / NCH; ns += 64) {
        const int n0 = n_start + ns;
        const int nn = t % 64, d0 = t / 64;
#pragma unroll
        for (int r = 0; r < 16; r++) {
            int d = d0 + r * 4;
            sk[d][nn] = kbase[(size_t)d * L + n0 + nn];
            sv[d][nn] = vbase[(size_t)d * L + n0 + nn];
        }
        __syncthreads();
#pragma unroll 8
        for (int q = 0; q < 64; q++) {
            float a[4], bb[4];
#pragma unroll
            for (int i = 0; i < 4; i++) a[i] = sk[ty * 4 + i][q];
#pragma unroll
            for (int j = 0; j < 4; j++) bb[j] = sv[tx * 4 + j][q];
#pragma unroll
            for (int i = 0; i < 4; i++)
#pragma unroll
                for (int j = 0; j < 4; j++) acc[i][j] += a[i] * bb[j];
        }
        __syncthreads();
    }
    float* cp = ctx + ((size_t)chunk * 64 + bh) * 4096;
#pragma unroll
    for (int i = 0; i < 4; i++) {
        float4 v = make_float4(acc[i][0], acc[i][1], acc[i][2], acc[i][3]);
        *(float4*)(cp + (ty * 4 + i) * 64 + tx * 4) = v;
    }
}

// ---------------------------------------------------------------------------
// pv: out[l][c] (bf16, transposed!) = sum_d context[d,e] * q[d,n].
// Writes bf16 [l][512] into the dead k-region of qkv.
// ---------------------------------------------------------------------------
__global__ __launch_bounds__(256) void pv_kernel(float* __restrict__ qkv,
                                                 const float* __restrict__ ctx) {
    const int lc = blockIdx.x;
    const int bh = blockIdx.y;
    const int b = bh >> 3, h = bh & 7;
    __shared__ float sc[4096];
    const int t = threadIdx.x;
#pragma unroll
    for (int r = 0; r < 16; r++) {
        const int idx = t + r * 256;
        float s = 0.f;
        for (int ch = 0; ch < NCH; ch++)
            s += ctx[((size_t)ch * 64 + bh) * 4096 + idx];
        sc[idx] = s;
    }
    __syncthreads();
    const float* qbase = qkv + (size_t)b * 1536 * L + (size_t)(h * 64) * L;
    const int n = lc * 256 + t;
    float acc[64] = {};
#pragma unroll 4
    for (int d = 0; d < 64; d++) {
        const float qv = qbase[(size_t)d * L + n];
#pragma unroll
        for (int e = 0; e < 64; e++) acc[e] += sc[d * 64 + e] * qv;
    }
    // transposed bf16 write: outT[b][n][h*64+e]
    __bf16* ob = (__bf16*)(qkv + (size_t)b * 1536 * L + (size_t)512 * L) + (size_t)n * 512 + h * 64;
#pragma unroll
    for (int e0 = 0; e0 < 64; e0 += 8) {
        bf16x8 pk;
#pragma unroll
        for (int j = 0; j < 8; j++) pk[j] = (__bf16)acc[e0 + j];
        *(bf16x8*)(ob + e0) = pk;
    }
}

// ---------------------------------------------------------------------------
extern "C" void kernel_launch(void* const* d_in, const int* in_sizes, int n_in,
                              void* d_out, int out_size, void* d_ws, size_t ws_size,
                              hipStream_t stream) {
    const float* x    = (const float*)d_in[0];
    const float* Wqkv = (const float*)d_in[1];
    const float* Wout = (const float*)d_in[2];
    const float* bout = (const float*)d_in[3];
    float* y = (float*)d_out;

    float*  qkv = (float*)d_ws;                                  // 8*1536*4096 f32
    float*  ctx = qkv + (size_t)8 * 1536 * L;                    // NCH*64*4096 f32
    __bf16* xb  = (__bf16*)(ctx + (size_t)NCH * 64 * 4096);      // 8*4096*512 bf16
    __bf16* Wqb = xb + (size_t)8 * 4096 * 512;                   // 1536*512 bf16
    __bf16* Wob = Wqb + (size_t)1536 * 512;                      // 512*512 bf16

    // conversions
    f32_to_bf16<<<dim3((8 * 4096 * 512 / 8 + 255) / 256), 256, 0, stream>>>(x, xb, 8 * 4096 * 512 / 8);
    f32_to_bf16<<<dim3((1536 * 512 / 8 + 255) / 256), 256, 0, stream>>>(Wqkv, Wqb, 1536 * 512 / 8);
    f32_to_bf16<<<dim3((512 * 512 / 8 + 255) / 256), 256, 0, stream>>>(Wout, Wob, 512 * 512 / 8);

    // qkv[b][o][l] = sum_d Wqkv[o][d] * x[b][l][d]   (M=1536, N=4096, K=512)
    gemm_bf16_mfma<1536, 4096, 512><<<dim3(4096 / 128, 1536 / 128, 8), 256, 0, stream>>>(
        Wqb, 0, xb, (size_t)4096 * 512, qkv, (size_t)1536 * 4096, nullptr);

    softmax_k<<<dim3(4096), 256, 0, stream>>>(qkv);
    softmax_q<<<dim3(1024), 256, 0, stream>>>(qkv);
    context_partial<<<dim3(NCH, 64), 256, 0, stream>>>(qkv, ctx);
    pv_kernel<<<dim3(L / 256, 64), 256, 0, stream>>>(qkv, ctx);

    // y[b][l][d] = sum_c outT[b][l][c] * Wout[d][c] + bout[d]  (M=4096, N=512, K=512)
    const __bf16* outT = (const __bf16*)(qkv + (size_t)512 * L);
    gemm_bf16_mfma<4096, 512, 512><<<dim3(512 / 128, 4096 / 128, 8), 256, 0, stream>>>(
        outT, (size_t)1536 * L * 2, Wob, 0, y, (size_t)4096 * 512, bout);
}